// Round 9
// baseline (1743.096 us; speedup 1.0000x reference)
//
#include <hip/hip_runtime.h>
#include <cstdint>
#include <cstddef>

// ----------------------------------------------------------------------------
// R9: convt on mfma_f32_32x32x16_bf16, 512-thr blocks, wm-wave B-dedup via L1.
// MFR=1 (acc 64 VGPR), LDS-read wall halved, weight L2-traffic cut by wave
// duplication through L1. conv3 stays 4x32-ch chunks; w3 transposed per-chunk.
// Workspace (all within proven 135,073,792):
//   y2   @ 0           64MB  [2048][64][256] bf16
//   y1   @ 67108864    32MB  (dead after conv2)
//   y3c  @ 100663296   32MB  [2048][256][32] bf16 (conv3 chunk)
//   w1t  @ 100663296   15.6MB (dead after conv1, aliases y3c)
//   w2t  @ 117047296   4MB   (dead after conv2, aliases y3c tail)
//   vals @ 134217728, idxs @ 134627328 (dead after conv1)
//   sp   @ 134217728 256KB, sqp @ 134479872 256KB (post-conv1, alias vals/idxs)
//   ac   @ 134742016 2KB, bc @ 134744064 2KB
//   w3tc @ 134746112 256KB [32][16][256] bf16 (per-chunk, regenerated)
// ----------------------------------------------------------------------------

typedef unsigned short u16;
typedef unsigned int u32;
typedef __attribute__((ext_vector_type(8))) short s16x8;    // 8 bf16 (4 VGPR)
typedef __attribute__((ext_vector_type(16))) float f32x16;  // 32x32 acc

static __device__ __forceinline__ float bf2f(u16 u) {
  union { u32 i; float f; } v; v.i = ((u32)u) << 16; return v.f;
}
static __device__ __forceinline__ u16 f2bf(float f) {  // RNE
  union { float f; u32 i; } v; v.f = f;
  const u32 r = v.i + 0x7fffu + ((v.i >> 16) & 1u);
  return (u16)(r >> 16);
}
// barrier that waits only LDS ops -> in-flight global loads cross it
static __device__ __forceinline__ void lds_barrier() {
  asm volatile("s_waitcnt lgkmcnt(0)" ::: "memory");
  __builtin_amdgcn_s_barrier();
}

// ---------------- top-k(50): one wave per row, all in registers -------------
__global__ __launch_bounds__(256) void topk_kernel(const float* __restrict__ x,
                                                   float* __restrict__ vals,
                                                   int* __restrict__ idxs) {
  const int lane = threadIdx.x & 63;
  const int b = blockIdx.x * 4 + (threadIdx.x >> 6);
  float v[16];
  #pragma unroll
  for (int j = 0; j < 16; ++j) {
    const int idx = lane + 64 * j;
    v[j] = (idx < 1000) ? x[(size_t)b * 1000 + idx] : -INFINITY;
  }
  float keepv = 1.0f;
  int keepi = 0;
  for (int k = 0; k < 50; ++k) {
    float bv = v[0]; int bj = 0;
    #pragma unroll
    for (int j = 1; j < 16; ++j)
      if (v[j] > bv) { bv = v[j]; bj = j; }
    int bi = lane + 64 * bj;
    #pragma unroll
    for (int off = 1; off < 64; off <<= 1) {
      const float ov = __shfl_xor(bv, off);
      const int oi = __shfl_xor(bi, off);
      if (ov > bv || (ov == bv && oi < bi)) { bv = ov; bi = oi; }
    }
    const int slot = bi >> 6;
    const bool own = (lane == (bi & 63));
    #pragma unroll
    for (int j = 0; j < 16; ++j)
      if (own && slot == j) v[j] = -INFINITY;
    if (lane == k) { keepv = bv; keepi = bi; }
  }
  const float tk = fmaxf(logf(keepv), -1000.0f) + 50.0f;
  float m = (lane < 50) ? tk : INFINITY;
  #pragma unroll
  for (int off = 1; off < 64; off <<= 1) m = fminf(m, __shfl_xor(m, off));
  const float shift = fmaxf(-m, 0.0f);
  if (lane < 50) {
    vals[b * 50 + lane] = tk + shift;
    idxs[b * 50 + lane] = keepi;
  }
}

// ---------------- w1 transpose: [1000][512][16] f32 -> [1000][16][512] bf16 -
__global__ __launch_bounds__(256) void w1t_kernel(const float* __restrict__ w1,
                                                  u16* __restrict__ w1t) {
  const int cin = blockIdx.x;
  const int t = threadIdx.x;
  __shared__ float is[512 * 17];
  const float* src = w1 + (size_t)cin * 8192;
  #pragma unroll
  for (int r = 0; r < 8; ++r) {
    const int f = r * 1024 + t * 4;
    const float4 v = *reinterpret_cast<const float4*>(src + f);
    const int co = f >> 4, s = f & 15;
    is[co * 17 + s + 0] = v.x;
    is[co * 17 + s + 1] = v.y;
    is[co * 17 + s + 2] = v.z;
    is[co * 17 + s + 3] = v.w;
  }
  __syncthreads();
  u16* dst = w1t + (size_t)cin * 8192;
  #pragma unroll
  for (int p = 0; p < 4; ++p) {
    const int i8 = (p * 256 + t) * 8;
    const int s = i8 >> 9, co = i8 & 511;
    union { u16 h[8]; s16x8 v; } pk;
    #pragma unroll
    for (int q = 0; q < 8; ++q) pk.h[q] = f2bf(is[(co + q) * 17 + s]);
    *reinterpret_cast<s16x8*>(dst + i8) = pk.v;
  }
}

// ------- weight transpose slice: [CIN][COUT][16] f32 -> [no][16][CIN] bf16 --
template <int CIN, int COUT>
__global__ __launch_bounds__(256) void wtc_kernel(const float* __restrict__ w,
                                                  u16* __restrict__ wt,
                                                  int obase) {
  const int o = obase + blockIdx.x;
  const int t = threadIdx.x;
  __shared__ __align__(16) u16 tile[16 * CIN];
  for (int c = t; c < CIN; c += 256) {
    const float* src = w + ((size_t)c * COUT + o) * 16;
    #pragma unroll
    for (int q4 = 0; q4 < 4; ++q4) {
      const float4 v = *reinterpret_cast<const float4*>(src + q4 * 4);
      tile[(q4 * 4 + 0) * CIN + c] = f2bf(v.x);
      tile[(q4 * 4 + 1) * CIN + c] = f2bf(v.y);
      tile[(q4 * 4 + 2) * CIN + c] = f2bf(v.z);
      tile[(q4 * 4 + 3) * CIN + c] = f2bf(v.w);
    }
  }
  __syncthreads();
  u16* dst = wt + (size_t)blockIdx.x * 16 * CIN;
  for (int i8 = t * 8; i8 < 16 * CIN; i8 += 2048)
    *reinterpret_cast<s16x8*>(dst + i8) = *reinterpret_cast<const s16x8*>(tile + i8);
}

// ---------------- conv1: sparse gather, channels-last y1 [2048][16][512] ----
__global__ __launch_bounds__(256) void conv1_kernel(const float* __restrict__ vals,
                                                    const int* __restrict__ idxs,
                                                    const u16* __restrict__ w1t,
                                                    const float* __restrict__ b1,
                                                    u16* __restrict__ y1) {
  const int b = blockIdx.x;
  const int t = threadIdx.x;
  __shared__ float sval[50];
  __shared__ int sidx[50];
  if (t < 50) { sval[t] = vals[b * 50 + t]; sidx[t] = idxs[b * 50 + t]; }
  __syncthreads();
  const int co = (t & 63) * 8;
  const int s0 = t >> 6;
  float b8[8];
  #pragma unroll
  for (int q = 0; q < 8; ++q) b8[q] = b1[co + q];
  #pragma unroll
  for (int sp = 0; sp < 4; ++sp) {
    const int s = sp * 4 + s0;
    float acc[8] = {0.f, 0.f, 0.f, 0.f, 0.f, 0.f, 0.f, 0.f};
    for (int j = 0; j < 50; ++j) {
      const float v = sval[j];
      union { s16x8 v8; u16 h[8]; } w;
      w.v8 = *reinterpret_cast<const s16x8*>(w1t + (size_t)sidx[j] * 8192 + s * 512 + co);
      #pragma unroll
      for (int q = 0; q < 8; ++q) acc[q] = fmaf(v, bf2f(w.h[q]), acc[q]);
    }
    union { u16 h[8]; s16x8 v8; } o;
    #pragma unroll
    for (int q = 0; q < 8; ++q) o.h[q] = f2bf(acc[q] + b8[q]);
    *reinterpret_cast<s16x8*>(y1 + (size_t)b * 8192 + s * 512 + co) = o.v8;
  }
}

// ---------------- BN stats (y1 only), channels-last [ROWS][C], 128 splits ---
__global__ __launch_bounds__(256) void bnstats_kernel(const u16* __restrict__ y,
                                                      float* __restrict__ sp,
                                                      float* __restrict__ sqp,
                                                      int C, int CB, int ROWS) {
  const int PB = CB >> 1;
  const int PR = 256 / PB;
  const int t = threadIdx.x;
  const int cp = t & (PB - 1);
  const int rl = t / PB;
  const int cbase = blockIdx.x * CB;
  const int split = blockIdx.y;
  const int RPB = ROWS >> 7;
  const u16* base = y + (size_t)split * RPB * C + cbase + 2 * cp;
  float s0 = 0.f, s1 = 0.f, q0 = 0.f, q1 = 0.f;
  for (int r = rl; r < RPB; r += PR) {
    const u32 raw = *reinterpret_cast<const u32*>(base + (size_t)r * C);
    const float a = bf2f((u16)(raw & 0xffffu));
    const float b = bf2f((u16)(raw >> 16));
    s0 += a; s1 += b;
    q0 = fmaf(a, a, q0); q1 = fmaf(b, b, q1);
  }
  __shared__ float4 arr[256];
  arr[t] = make_float4(s0, s1, q0, q1);
  __syncthreads();
  if (t < PB) {
    float4 acc = arr[t];
    for (int g = 1; g < PR; ++g) {
      const float4 v = arr[g * PB + t];
      acc.x += v.x; acc.y += v.y; acc.z += v.z; acc.w += v.w;
    }
    const int c = cbase + 2 * t;
    sp[split * C + c] = acc.x;
    sp[split * C + c + 1] = acc.y;
    sqp[split * C + c] = acc.z;
    sqp[split * C + c + 1] = acc.w;
  }
}

// ---------------- BN finalize, variable split count / channel count ---------
__global__ __launch_bounds__(256) void bnfin_kernel(const float* __restrict__ sp,
                                                    const float* __restrict__ sqp,
                                                    const float* __restrict__ g,
                                                    const float* __restrict__ be,
                                                    float* __restrict__ a,
                                                    float* __restrict__ bb,
                                                    int logC, int SPLITS, float inv) {
  const int t = threadIdx.x;
  const int C = 1 << logC;
  const int lc = t & (C - 1);
  int PARTS = 256 >> logC;
  if (PARTS == 0) PARTS = 1;
  const int part = (logC >= 8) ? 0 : (t >> logC);
  const int chunk = SPLITS / PARTS;
  const int c = (blockIdx.x << 8) + lc;
  float s = 0.f, s2 = 0.f;
  for (int k = part * chunk; k < (part + 1) * chunk; ++k) {
    s += sp[(size_t)k * C + c];
    s2 += sqp[(size_t)k * C + c];
  }
  __shared__ float rs[256], rq[256];
  rs[t] = s; rq[t] = s2;
  __syncthreads();
  if (part == 0 && t < C) {
    for (int p = 1; p < PARTS; ++p) {
      s += rs[(p << logC) + lc];
      s2 += rq[(p << logC) + lc];
    }
    const float m = s * inv;
    float var = fmaf(-m, m, s2 * inv);
    var = fmaxf(var, 0.f);
    const float r = 1.0f / sqrtf(var + 1e-5f);
    const float av = g[c] * r;
    a[c] = av;
    bb[c] = fmaf(-m, av, be[c]);
  }
}

// ---------------- BN affine + tanh in place, channels-last ------------------
__global__ __launch_bounds__(256) void bnact_kernel(u16* __restrict__ y,
                                                    const float* __restrict__ a,
                                                    const float* __restrict__ bb,
                                                    int Cm1) {
  const size_t i = ((size_t)blockIdx.x * 256 + threadIdx.x) * 8;
  const int c = (int)i & Cm1;
  uint4 raw = *reinterpret_cast<uint4*>(y + i);
  float av[8], bv[8];
  *reinterpret_cast<float4*>(av) = *reinterpret_cast<const float4*>(a + c);
  *reinterpret_cast<float4*>(av + 4) = *reinterpret_cast<const float4*>(a + c + 4);
  *reinterpret_cast<float4*>(bv) = *reinterpret_cast<const float4*>(bb + c);
  *reinterpret_cast<float4*>(bv + 4) = *reinterpret_cast<const float4*>(bb + c + 4);
  u32 w[4] = {raw.x, raw.y, raw.z, raw.w};
  #pragma unroll
  for (int q = 0; q < 4; ++q) {
    const float lo = tanhf(fmaf(bf2f((u16)(w[q] & 0xffffu)), av[2 * q], bv[2 * q]));
    const float hi = tanhf(fmaf(bf2f((u16)(w[q] >> 16)), av[2 * q + 1], bv[2 * q + 1]));
    w[q] = (u32)f2bf(lo) | ((u32)f2bf(hi) << 16);
  }
  raw.x = w[0]; raw.y = w[1]; raw.z = w[2]; raw.w = w[3];
  *reinterpret_cast<uint4*>(y + i) = raw;
}

// ---------------- MFMA convT k=4 s=2 p=1 on 32x32x16, 512 threads -----------
// in: [B][SIN*SIN][CIN] bf16 channels-last. wt: [gridX*WN*32][16][CIN] bf16
// (chunk-local channel order). out: [B][4*SIN*SIN][COUT_STORE] bf16.
// 8 waves = WM x WN; MFR=1 (each wave: 32 rows x WN-slice of 32 channels).
// wm-waves share identical B-fragments -> L1 dedup. Fused BN partial sums.
template <int SIN, int CIN, int WM, int WN, int MBATCH, int COUT_STORE>
__global__ __launch_bounds__(512, 2) void convt_mfma(const u16* __restrict__ in,
                                                     const u16* __restrict__ wt,
                                                     const float* __restrict__ bias,
                                                     u16* __restrict__ outp,
                                                     float* __restrict__ spp,
                                                     float* __restrict__ sqpp,
                                                     int o_gbase) {
  constexpr int SS = SIN * SIN;
  constexpr int MB = MBATCH * SS;          // input rows per block (= WM*32)
  constexpr int NB = WN * 32;              // out channels per block
  constexpr int LOGS = (SIN == 4) ? 2 : 3;
  constexpr int NPASS = MB / 64;           // staging passes (64 rows per pass)
  constexpr int NSTEP = CIN / 64;          // K steps
  constexpr int BUFW = (MB + 1) * 64;      // u16 per buffer (row MB = zeros)
  constexpr int KYT[2][2] = {{1, 3}, {2, 0}};
  constexpr int DYT[2][2] = {{0, -1}, {0, 1}};
  static_assert(WM * WN == 8, "8 waves");
  static_assert(MB == WM * 32, "MFR==1");
  __shared__ __align__(16) u16 As[2 * BUFW];
  __shared__ float sred[512];              // [wave][ch] sums | +256 sumsq

  const int t = threadIdx.x;
  const int lane = t & 63;
  const int wave = t >> 6;
  const int wn = wave % WN;
  const int wm = wave / WN;
  const int l31 = lane & 31;
  const int kl2 = lane >> 5;
  const int bx = blockIdx.x;
  const int R0 = blockIdx.y * MB;

  // per-lane LDS byte offsets for the 9 shifts (row = wm*32 + l31)
  int rb[9];
  {
    const int r = wm * 32 + l31;
    const int bl = r >> (2 * LOGS);
    const int rr = r & (SS - 1);
    const int sy = rr >> LOGS, sx = rr & (SIN - 1);
    #pragma unroll
    for (int dyi = 0; dyi < 3; ++dyi)
      #pragma unroll
      for (int dxi = 0; dxi < 3; ++dxi) {
        const int ny = sy + dyi - 1, nx = sx + dxi - 1;
        const bool ok = (ny >= 0 && ny < SIN && nx >= 0 && nx < SIN);
        const int rp = ok ? ((bl << (2 * LOGS)) + (ny << LOGS) + nx) : MB;
        rb[dyi * 3 + dxi] = (rp << 7) | ((rp & 7) << 4);
      }
  }
  if (t < 16) {  // zero sentinel row of both buffers
    s16x8 z = {};
    const int buf = t >> 3;
    *reinterpret_cast<s16x8*>(As + buf * BUFW + MB * 64 + (t & 7) * 8) = z;
  }

  f32x16 acc[2][2];
  #pragma unroll
  for (int py = 0; py < 2; ++py)
    #pragma unroll
    for (int px = 0; px < 2; ++px) acc[py][px] = (f32x16)(0.f);

  const int ocw = bx * NB + wn * 32 + l31;        // wt-local out channel
  const u16* wptr = wt + (size_t)ocw * 16 * CIN + kl2 * 8;

  // staging geometry: row = p*64 + (t>>3), 16B at col (t&7)*8
  const int srow = t >> 3;
  const int scol = (t & 7) * 8;
  const u16* gsrc = in + (size_t)(R0 + srow) * CIN + scol;

  s16x8 sreg[NPASS];
  #pragma unroll
  for (int p = 0; p < NPASS; ++p)
    sreg[p] = *reinterpret_cast<const s16x8*>(gsrc + (size_t)p * 64 * CIN);

  int cur = 0;
  for (int s = 0; s < NSTEP; ++s) {
    u16* dbuf = As + cur * BUFW;
    #pragma unroll
    for (int p = 0; p < NPASS; ++p) {
      const int row = p * 64 + srow;
      const int db = row * 128 + ((scol * 2) ^ ((row & 7) << 4));
      *reinterpret_cast<s16x8*>((char*)dbuf + db) = sreg[p];
    }
    if (s + 1 < NSTEP) {
      const u16* gn = gsrc + (s + 1) * 64;
      #pragma unroll
      for (int p = 0; p < NPASS; ++p)
        sreg[p] = *reinterpret_cast<const s16x8*>(gn + (size_t)p * 64 * CIN);
    }
    lds_barrier();   // lgkmcnt(0) only; prefetch stays in flight

    const u16* Ab = As + cur * BUFW;
    const int c0 = s * 64;
    #pragma unroll
    for (int ksub = 0; ksub < 4; ++ksub) {
      // B fragments for this K=16 slice (identical across wm-waves -> L1 hit)
      const u16* wp = wptr + c0 + ksub * 16;
      s16x8 bf[2][2][2][2];
      #pragma unroll
      for (int py = 0; py < 2; ++py)
        #pragma unroll
        for (int px = 0; px < 2; ++px)
          #pragma unroll
          for (int jy = 0; jy < 2; ++jy)
            #pragma unroll
            for (int jx = 0; jx < 2; ++jx) {
              const int tap = KYT[py][jy] * 4 + KYT[px][jx];
              bf[py][px][jy][jx] =
                  *reinterpret_cast<const s16x8*>(wp + (size_t)tap * CIN);
            }
      // A fragments: 9 shifts
      const int koff = ksub * 32 + kl2 * 16;
      s16x8 af[9];
      #pragma unroll
      for (int s9 = 0; s9 < 9; ++s9)
        af[s9] = *reinterpret_cast<const s16x8*>((const char*)Ab + (rb[s9] ^ koff));
      __builtin_amdgcn_s_setprio(1);
      #pragma unroll
      for (int py = 0; py < 2; ++py)
        #pragma unroll
        for (int px = 0; px < 2; ++px)
          #pragma unroll
          for (int jy = 0; jy < 2; ++jy)
            #pragma unroll
            for (int jx = 0; jx < 2; ++jx) {
              const int s9 = (DYT[py][jy] + 1) * 3 + (DYT[px][jx] + 1);
              acc[py][px] = __builtin_amdgcn_mfma_f32_32x32x16_bf16(
                  af[s9], bf[py][px][jy][jx], acc[py][px], 0, 0, 0);
            }
      __builtin_amdgcn_s_setprio(0);
    }
    cur ^= 1;
  }

  // epilogue: store + fused per-channel BN partials (fp32, pre-rounding)
  const float bo = bias[o_gbase + ocw];
  const int B0 = blockIdx.y * MBATCH;
  float s_ = 0.f, q_ = 0.f;
  #pragma unroll
  for (int i = 0; i < 16; ++i) {
    const int rl_ = (i & 3) + 8 * (i >> 2) + 4 * kl2;
    const int r = wm * 32 + rl_;
    const int bl = r >> (2 * LOGS);
    const int rr = r & (SS - 1);
    const int sy = rr >> LOGS, sx = rr & (SIN - 1);
    const size_t ob = (size_t)(B0 + bl) * 4 * SS;
    #pragma unroll
    for (int py = 0; py < 2; ++py)
      #pragma unroll
      for (int px = 0; px < 2; ++px) {
        const int od = (2 * sy + py) * (2 * SIN) + 2 * sx + px;
        const float v = acc[py][px][i] + bo;
        s_ += v;
        q_ = fmaf(v, v, q_);
        outp[(ob + od) * COUT_STORE + ocw] = f2bf(v);
      }
  }
  s_ += __shfl_xor(s_, 32);
  q_ += __shfl_xor(q_, 32);
  if (lane < 32) {
    sred[wave * 32 + l31] = s_;
    sred[256 + wave * 32 + l31] = q_;
  }
  __syncthreads();
  if (t < WN * 32) {
    const int wnr = t >> 5;
    const int ch = t & 31;
    float ss = 0.f, qq = 0.f;
    #pragma unroll
    for (int w = 0; w < WM; ++w) {
      ss += sred[(w * WN + wnr) * 32 + ch];
      qq += sred[256 + (w * WN + wnr) * 32 + ch];
    }
    const int c = bx * NB + wnr * 32 + ch;
    spp[(size_t)blockIdx.y * COUT_STORE + c] = ss;
    sqpp[(size_t)blockIdx.y * COUT_STORE + c] = qq;
  }
}

// ---------------- conv4: fused BN-affine+tanh + convT(128->1) + sigmoid -----
__global__ __launch_bounds__(256) void conv4_kernel(const u16* __restrict__ h3c,
                                                    const float* __restrict__ ac,
                                                    const float* __restrict__ bc,
                                                    const float* __restrict__ w4,
                                                    const float* __restrict__ b4,
                                                    float* __restrict__ outp,
                                                    int cbase, int last) {
  const int b = blockIdx.x;
  const int t = threadIdx.x;
  __shared__ float wsh[32 * 16];
  __shared__ float is[32 * 257];
  for (int i = t; i < 512; i += 256) wsh[i] = w4[cbase * 16 + i];
  const int cq = (t & 3) * 8;
  float av[8], bv[8];
  *reinterpret_cast<float4*>(av)     = *reinterpret_cast<const float4*>(ac + cq);
  *reinterpret_cast<float4*>(av + 4) = *reinterpret_cast<const float4*>(ac + cq + 4);
  *reinterpret_cast<float4*>(bv)     = *reinterpret_cast<const float4*>(bc + cq);
  *reinterpret_cast<float4*>(bv + 4) = *reinterpret_cast<const float4*>(bc + cq + 4);
  #pragma unroll
  for (int p = 0; p < 4; ++p) {
    const int idx8 = p * 256 + t;
    const int s = idx8 >> 2;
    union { s16x8 v8; u16 h[8]; } r;
    r.v8 = *reinterpret_cast<const s16x8*>(h3c + ((size_t)b * 256 + s) * 32 + cq);
    #pragma unroll
    for (int q = 0; q < 8; ++q)
      is[(cq + q) * 257 + s] = tanhf(fmaf(bf2f(r.h[q]), av[q], bv[q]));
  }
  __syncthreads();
  float acc[4] = {0.f, 0.f, 0.f, 0.f};
  const int ox = t & 31;
  const int oy0 = t >> 5;
  for (int c = 0; c < 32; ++c) {
    #pragma unroll
    for (int k = 0; k < 4; ++k) {
      const int oy = oy0 + 8 * k;
      #pragma unroll
      for (int jy = 0; jy < 2; ++jy) {
        const int ky = 2 * jy + 1 - (oy & 1);
        const int iyn = oy + 1 - ky;
        if ((unsigned)iyn < 32u) {
          const int iy = iyn >> 1;
          #pragma unroll
          for (int jx = 0; jx < 2; ++jx) {
            const int kx = 2 * jx + 1 - (ox & 1);
            const int ixn = ox + 1 - kx;
            if ((unsigned)ixn < 32u) {
              const int ix = ixn >> 1;
              acc[k] = fmaf(is[c * 257 + iy * 16 + ix], wsh[c * 16 + ky * 4 + kx], acc[k]);
            }
          }
        }
      }
    }
  }
  #pragma unroll
  for (int k = 0; k < 4; ++k) {
    const int oy = oy0 + 8 * k;
    const size_t ob = (size_t)b * 1024 + oy * 32 + ox;
    const float base = (cbase == 0) ? b4[0] : outp[ob];
    const float v = base + acc[k];
    outp[ob] = last ? (1.0f / (1.0f + expf(-v))) : v;
  }
}

// ----------------------------------------------------------------------------
extern "C" void kernel_launch(void* const* d_in, const int* in_sizes, int n_in,
                              void* d_out, int out_size, void* d_ws, size_t ws_size,
                              hipStream_t stream) {
  (void)in_sizes; (void)n_in; (void)out_size; (void)ws_size;
  const float* x   = (const float*)d_in[0];
  const float* w1  = (const float*)d_in[1];
  const float* b1  = (const float*)d_in[2];
  const float* g1  = (const float*)d_in[3];
  const float* be1 = (const float*)d_in[4];
  const float* w2  = (const float*)d_in[5];
  const float* b2  = (const float*)d_in[6];
  const float* g2  = (const float*)d_in[7];
  const float* be2 = (const float*)d_in[8];
  const float* w3  = (const float*)d_in[9];
  const float* b3  = (const float*)d_in[10];
  const float* g3  = (const float*)d_in[11];
  const float* be3 = (const float*)d_in[12];
  const float* w4  = (const float*)d_in[13];
  const float* b4  = (const float*)d_in[14];

  char* ws = (char*)d_ws;
  u16*   y2   = (u16*)(ws + 0);
  u16*   y1   = (u16*)(ws + 67108864);
  u16*   y3c  = (u16*)(ws + 100663296);
  u16*   w1t  = (u16*)(ws + 100663296);   // dead after conv1 (aliases y3c)
  u16*   w2t  = (u16*)(ws + 117047296);   // dead after conv2 (aliases y3c)
  float* vals = (float*)(ws + 134217728);
  int*   idxs = (int*)(ws + 134627328);
  float* sp   = (float*)(ws + 134217728); // post-conv1 (aliases vals)
  float* sqp  = (float*)(ws + 134479872);
  float* ac   = (float*)(ws + 134742016);
  float* bc   = (float*)(ws + 134744064);
  u16*   w3tc = (u16*)(ws + 134746112);   // 256KB per-chunk w3 transpose
  float* outp = (float*)d_out;

  // precomputes + truncation vector
  w1t_kernel<<<1000, 256, 0, stream>>>(w1, w1t);
  wtc_kernel<512, 256><<<256, 256, 0, stream>>>(w2, w2t, 0);
  topk_kernel<<<512, 256, 0, stream>>>(x, vals, idxs);

  // layer 1
  conv1_kernel<<<2048, 256, 0, stream>>>(vals, idxs, w1t, b1, y1);
  bnstats_kernel<<<dim3(4, 128), 256, 0, stream>>>(y1, sp, sqp, 512, 128, 32768);
  bnfin_kernel<<<2, 256, 0, stream>>>(sp, sqp, g1, be1, ac, bc, 9, 128, 1.0f / 32768.0f);
  bnact_kernel<<<8192, 256, 0, stream>>>(y1, ac, bc, 511);

  // layer 2: convT 512->256 on 32x32 MFMA, fused stats
  convt_mfma<4, 512, 4, 2, 8, 256><<<dim3(4, 256), 512, 0, stream>>>(
      y1, w2t, b2, y2, sp, sqp, 0);
  bnfin_kernel<<<1, 256, 0, stream>>>(sp, sqp, g2, be2, ac, bc, 8, 256, 1.0f / 131072.0f);
  bnact_kernel<<<16384, 256, 0, stream>>>(y2, ac, bc, 255);

  // layer 3+4: convT 256->128 in 4 chunks of 32 oc (per-chunk w3 transpose);
  // fused stats; conv4 applies BN-affine+tanh and accumulates into d_out
  for (int ch = 0; ch < 4; ++ch) {
    const int cb = ch * 32;
    wtc_kernel<256, 128><<<32, 256, 0, stream>>>(w3, w3tc, cb);
    convt_mfma<8, 256, 8, 1, 4, 32><<<dim3(1, 512), 512, 0, stream>>>(
        y2, w3tc, b3, y3c, sp, sqp, cb);
    bnfin_kernel<<<1, 256, 0, stream>>>(sp, sqp, g3 + cb, be3 + cb, ac, bc, 5, 512,
                                        1.0f / 524288.0f);
    conv4_kernel<<<2048, 256, 0, stream>>>(y3c, ac, bc, w4, b4, outp, cb, ch == 3);
  }
}

// Round 10
// 1120.175 us; speedup vs baseline: 1.5561x; 1.5561x over previous
//
#include <hip/hip_runtime.h>
#include <cstdint>
#include <cstddef>

// ----------------------------------------------------------------------------
// R10: R9 + coalesced B-weight layout wt2[tap][kb][ch][kk] so each 32x32 MFMA
// B-fragment load is 1KB contiguous (8 cache lines) instead of 64 scattered
// lines. Single change vs R9; everything else identical.
// Workspace (all within proven 135,073,792):
//   y2   @ 0           64MB  [2048][64][256] bf16
//   y1   @ 67108864    32MB  (dead after conv2)
//   y3c  @ 100663296   32MB  [2048][256][32] bf16 (conv3 chunk)
//   w1t  @ 100663296   15.6MB (dead after conv1, aliases y3c)
//   w2t  @ 117047296   4MB   (dead after conv2, aliases y3c)
//   vals @ 134217728, idxs @ 134627328 (dead after conv1)
//   sp   @ 134217728 256KB, sqp @ 134479872 256KB (post-conv1, alias vals/idxs)
//   ac   @ 134742016 2KB, bc @ 134744064 2KB
//   w3tc @ 134746112 256KB [16][16][32][16] bf16 (per-chunk, regenerated)
// ----------------------------------------------------------------------------

typedef unsigned short u16;
typedef unsigned int u32;
typedef __attribute__((ext_vector_type(8))) short s16x8;    // 8 bf16 (4 VGPR)
typedef __attribute__((ext_vector_type(16))) float f32x16;  // 32x32 acc

static __device__ __forceinline__ float bf2f(u16 u) {
  union { u32 i; float f; } v; v.i = ((u32)u) << 16; return v.f;
}
static __device__ __forceinline__ u16 f2bf(float f) {  // RNE
  union { float f; u32 i; } v; v.f = f;
  const u32 r = v.i + 0x7fffu + ((v.i >> 16) & 1u);
  return (u16)(r >> 16);
}
// barrier that waits only LDS ops -> in-flight global loads cross it
static __device__ __forceinline__ void lds_barrier() {
  asm volatile("s_waitcnt lgkmcnt(0)" ::: "memory");
  __builtin_amdgcn_s_barrier();
}

// ---------------- top-k(50): one wave per row, all in registers -------------
__global__ __launch_bounds__(256) void topk_kernel(const float* __restrict__ x,
                                                   float* __restrict__ vals,
                                                   int* __restrict__ idxs) {
  const int lane = threadIdx.x & 63;
  const int b = blockIdx.x * 4 + (threadIdx.x >> 6);
  float v[16];
  #pragma unroll
  for (int j = 0; j < 16; ++j) {
    const int idx = lane + 64 * j;
    v[j] = (idx < 1000) ? x[(size_t)b * 1000 + idx] : -INFINITY;
  }
  float keepv = 1.0f;
  int keepi = 0;
  for (int k = 0; k < 50; ++k) {
    float bv = v[0]; int bj = 0;
    #pragma unroll
    for (int j = 1; j < 16; ++j)
      if (v[j] > bv) { bv = v[j]; bj = j; }
    int bi = lane + 64 * bj;
    #pragma unroll
    for (int off = 1; off < 64; off <<= 1) {
      const float ov = __shfl_xor(bv, off);
      const int oi = __shfl_xor(bi, off);
      if (ov > bv || (ov == bv && oi < bi)) { bv = ov; bi = oi; }
    }
    const int slot = bi >> 6;
    const bool own = (lane == (bi & 63));
    #pragma unroll
    for (int j = 0; j < 16; ++j)
      if (own && slot == j) v[j] = -INFINITY;
    if (lane == k) { keepv = bv; keepi = bi; }
  }
  const float tk = fmaxf(logf(keepv), -1000.0f) + 50.0f;
  float m = (lane < 50) ? tk : INFINITY;
  #pragma unroll
  for (int off = 1; off < 64; off <<= 1) m = fminf(m, __shfl_xor(m, off));
  const float shift = fmaxf(-m, 0.0f);
  if (lane < 50) {
    vals[b * 50 + lane] = tk + shift;
    idxs[b * 50 + lane] = keepi;
  }
}

// ---------------- w1 transpose: [1000][512][16] f32 -> [1000][16][512] bf16 -
__global__ __launch_bounds__(256) void w1t_kernel(const float* __restrict__ w1,
                                                  u16* __restrict__ w1t) {
  const int cin = blockIdx.x;
  const int t = threadIdx.x;
  __shared__ float is[512 * 17];
  const float* src = w1 + (size_t)cin * 8192;
  #pragma unroll
  for (int r = 0; r < 8; ++r) {
    const int f = r * 1024 + t * 4;
    const float4 v = *reinterpret_cast<const float4*>(src + f);
    const int co = f >> 4, s = f & 15;
    is[co * 17 + s + 0] = v.x;
    is[co * 17 + s + 1] = v.y;
    is[co * 17 + s + 2] = v.z;
    is[co * 17 + s + 3] = v.w;
  }
  __syncthreads();
  u16* dst = w1t + (size_t)cin * 8192;
  #pragma unroll
  for (int p = 0; p < 4; ++p) {
    const int i8 = (p * 256 + t) * 8;
    const int s = i8 >> 9, co = i8 & 511;
    union { u16 h[8]; s16x8 v; } pk;
    #pragma unroll
    for (int q = 0; q < 8; ++q) pk.h[q] = f2bf(is[(co + q) * 17 + s]);
    *reinterpret_cast<s16x8*>(dst + i8) = pk.v;
  }
}

// ---- weight transpose: [CIN][COUT][16] f32 -> wt2[tap][kb][ch][kk] bf16 ----
// wt2[((tap*(CIN/16) + kb)*NCH + ch)*16 + kk] = w[(kb*16+kk)*COUT + obase+ch][tap]
// One block: 1 kb x 32 channels.
template <int CIN, int COUT>
__global__ __launch_bounds__(256) void wt2_kernel(const float* __restrict__ w,
                                                  u16* __restrict__ wt2,
                                                  int obase, int NCH) {
  constexpr int KB = CIN / 16;
  const int kb = blockIdx.x;
  const int chg = blockIdx.y;
  const int t = threadIdx.x;
  __shared__ __align__(16) u16 tile[16 * 32 * 16];  // [tap][ch][kk]
  for (int i = t; i < 512; i += 256) {
    const int kk = i >> 5;
    const int ch = i & 31;
    const float* src = w + ((size_t)(kb * 16 + kk) * COUT + obase + chg * 32 + ch) * 16;
    #pragma unroll
    for (int q4 = 0; q4 < 4; ++q4) {
      const float4 v = *reinterpret_cast<const float4*>(src + q4 * 4);
      tile[(q4 * 4 + 0) * 512 + ch * 16 + kk] = f2bf(v.x);
      tile[(q4 * 4 + 1) * 512 + ch * 16 + kk] = f2bf(v.y);
      tile[(q4 * 4 + 2) * 512 + ch * 16 + kk] = f2bf(v.z);
      tile[(q4 * 4 + 3) * 512 + ch * 16 + kk] = f2bf(v.w);
    }
  }
  __syncthreads();
  for (int i = t; i < 16 * 64; i += 256) {
    const int tap = i >> 6;
    const int off = (i & 63) * 8;
    u16* dst = wt2 + ((size_t)(tap * KB + kb) * NCH + chg * 32) * 16 + off;
    *reinterpret_cast<s16x8*>(dst) = *reinterpret_cast<const s16x8*>(tile + tap * 512 + off);
  }
}

// ---------------- conv1: sparse gather, channels-last y1 [2048][16][512] ----
__global__ __launch_bounds__(256) void conv1_kernel(const float* __restrict__ vals,
                                                    const int* __restrict__ idxs,
                                                    const u16* __restrict__ w1t,
                                                    const float* __restrict__ b1,
                                                    u16* __restrict__ y1) {
  const int b = blockIdx.x;
  const int t = threadIdx.x;
  __shared__ float sval[50];
  __shared__ int sidx[50];
  if (t < 50) { sval[t] = vals[b * 50 + t]; sidx[t] = idxs[b * 50 + t]; }
  __syncthreads();
  const int co = (t & 63) * 8;
  const int s0 = t >> 6;
  float b8[8];
  #pragma unroll
  for (int q = 0; q < 8; ++q) b8[q] = b1[co + q];
  #pragma unroll
  for (int sp = 0; sp < 4; ++sp) {
    const int s = sp * 4 + s0;
    float acc[8] = {0.f, 0.f, 0.f, 0.f, 0.f, 0.f, 0.f, 0.f};
    for (int j = 0; j < 50; ++j) {
      const float v = sval[j];
      union { s16x8 v8; u16 h[8]; } w;
      w.v8 = *reinterpret_cast<const s16x8*>(w1t + (size_t)sidx[j] * 8192 + s * 512 + co);
      #pragma unroll
      for (int q = 0; q < 8; ++q) acc[q] = fmaf(v, bf2f(w.h[q]), acc[q]);
    }
    union { u16 h[8]; s16x8 v8; } o;
    #pragma unroll
    for (int q = 0; q < 8; ++q) o.h[q] = f2bf(acc[q] + b8[q]);
    *reinterpret_cast<s16x8*>(y1 + (size_t)b * 8192 + s * 512 + co) = o.v8;
  }
}

// ---------------- BN stats (y1 only), channels-last [ROWS][C], 128 splits ---
__global__ __launch_bounds__(256) void bnstats_kernel(const u16* __restrict__ y,
                                                      float* __restrict__ sp,
                                                      float* __restrict__ sqp,
                                                      int C, int CB, int ROWS) {
  const int PB = CB >> 1;
  const int PR = 256 / PB;
  const int t = threadIdx.x;
  const int cp = t & (PB - 1);
  const int rl = t / PB;
  const int cbase = blockIdx.x * CB;
  const int split = blockIdx.y;
  const int RPB = ROWS >> 7;
  const u16* base = y + (size_t)split * RPB * C + cbase + 2 * cp;
  float s0 = 0.f, s1 = 0.f, q0 = 0.f, q1 = 0.f;
  for (int r = rl; r < RPB; r += PR) {
    const u32 raw = *reinterpret_cast<const u32*>(base + (size_t)r * C);
    const float a = bf2f((u16)(raw & 0xffffu));
    const float b = bf2f((u16)(raw >> 16));
    s0 += a; s1 += b;
    q0 = fmaf(a, a, q0); q1 = fmaf(b, b, q1);
  }
  __shared__ float4 arr[256];
  arr[t] = make_float4(s0, s1, q0, q1);
  __syncthreads();
  if (t < PB) {
    float4 acc = arr[t];
    for (int g = 1; g < PR; ++g) {
      const float4 v = arr[g * PB + t];
      acc.x += v.x; acc.y += v.y; acc.z += v.z; acc.w += v.w;
    }
    const int c = cbase + 2 * t;
    sp[split * C + c] = acc.x;
    sp[split * C + c + 1] = acc.y;
    sqp[split * C + c] = acc.z;
    sqp[split * C + c + 1] = acc.w;
  }
}

// ---------------- BN finalize, variable split count / channel count ---------
__global__ __launch_bounds__(256) void bnfin_kernel(const float* __restrict__ sp,
                                                    const float* __restrict__ sqp,
                                                    const float* __restrict__ g,
                                                    const float* __restrict__ be,
                                                    float* __restrict__ a,
                                                    float* __restrict__ bb,
                                                    int logC, int SPLITS, float inv) {
  const int t = threadIdx.x;
  const int C = 1 << logC;
  const int lc = t & (C - 1);
  int PARTS = 256 >> logC;
  if (PARTS == 0) PARTS = 1;
  const int part = (logC >= 8) ? 0 : (t >> logC);
  const int chunk = SPLITS / PARTS;
  const int c = (blockIdx.x << 8) + lc;
  float s = 0.f, s2 = 0.f;
  for (int k = part * chunk; k < (part + 1) * chunk; ++k) {
    s += sp[(size_t)k * C + c];
    s2 += sqp[(size_t)k * C + c];
  }
  __shared__ float rs[256], rq[256];
  rs[t] = s; rq[t] = s2;
  __syncthreads();
  if (part == 0 && t < C) {
    for (int p = 1; p < PARTS; ++p) {
      s += rs[(p << logC) + lc];
      s2 += rq[(p << logC) + lc];
    }
    const float m = s * inv;
    float var = fmaf(-m, m, s2 * inv);
    var = fmaxf(var, 0.f);
    const float r = 1.0f / sqrtf(var + 1e-5f);
    const float av = g[c] * r;
    a[c] = av;
    bb[c] = fmaf(-m, av, be[c]);
  }
}

// ---------------- BN affine + tanh in place, channels-last ------------------
__global__ __launch_bounds__(256) void bnact_kernel(u16* __restrict__ y,
                                                    const float* __restrict__ a,
                                                    const float* __restrict__ bb,
                                                    int Cm1) {
  const size_t i = ((size_t)blockIdx.x * 256 + threadIdx.x) * 8;
  const int c = (int)i & Cm1;
  uint4 raw = *reinterpret_cast<uint4*>(y + i);
  float av[8], bv[8];
  *reinterpret_cast<float4*>(av) = *reinterpret_cast<const float4*>(a + c);
  *reinterpret_cast<float4*>(av + 4) = *reinterpret_cast<const float4*>(a + c + 4);
  *reinterpret_cast<float4*>(bv) = *reinterpret_cast<const float4*>(bb + c);
  *reinterpret_cast<float4*>(bv + 4) = *reinterpret_cast<const float4*>(bb + c + 4);
  u32 w[4] = {raw.x, raw.y, raw.z, raw.w};
  #pragma unroll
  for (int q = 0; q < 4; ++q) {
    const float lo = tanhf(fmaf(bf2f((u16)(w[q] & 0xffffu)), av[2 * q], bv[2 * q]));
    const float hi = tanhf(fmaf(bf2f((u16)(w[q] >> 16)), av[2 * q + 1], bv[2 * q + 1]));
    w[q] = (u32)f2bf(lo) | ((u32)f2bf(hi) << 16);
  }
  raw.x = w[0]; raw.y = w[1]; raw.z = w[2]; raw.w = w[3];
  *reinterpret_cast<uint4*>(y + i) = raw;
}

// ---------------- MFMA convT k=4 s=2 p=1 on 32x32x16, 512 threads -----------
// in: [B][SIN*SIN][CIN] bf16 channels-last. wt2: [16tap][CIN/16][NCHT][16] bf16
// (chunk-local channels, coalesced B-frags). out: [B][4*SIN*SIN][COUT_STORE].
// 8 waves = WM x WN, MFR=1. wm-waves share identical B-frags -> L1 dedup.
template <int SIN, int CIN, int WM, int WN, int MBATCH, int COUT_STORE>
__global__ __launch_bounds__(512, 2) void convt_mfma(const u16* __restrict__ in,
                                                     const u16* __restrict__ wt,
                                                     const float* __restrict__ bias,
                                                     u16* __restrict__ outp,
                                                     float* __restrict__ spp,
                                                     float* __restrict__ sqpp,
                                                     int o_gbase) {
  constexpr int SS = SIN * SIN;
  constexpr int MB = MBATCH * SS;          // input rows per block (= WM*32)
  constexpr int NB = WN * 32;              // out channels per block
  constexpr int KB = CIN / 16;             // k-blocks in wt2
  constexpr int LOGS = (SIN == 4) ? 2 : 3;
  constexpr int NPASS = MB / 64;           // staging passes (64 rows per pass)
  constexpr int NSTEP = CIN / 64;          // K steps
  constexpr int BUFW = (MB + 1) * 64;      // u16 per buffer (row MB = zeros)
  constexpr int KYT[2][2] = {{1, 3}, {2, 0}};
  constexpr int DYT[2][2] = {{0, -1}, {0, 1}};
  static_assert(WM * WN == 8, "8 waves");
  static_assert(MB == WM * 32, "MFR==1");
  __shared__ __align__(16) u16 As[2 * BUFW];
  __shared__ float sred[512];              // [wave][ch] sums | +256 sumsq

  const int t = threadIdx.x;
  const int lane = t & 63;
  const int wave = t >> 6;
  const int wn = wave % WN;
  const int wm = wave / WN;
  const int l31 = lane & 31;
  const int kl2 = lane >> 5;
  const int bx = blockIdx.x;
  const int R0 = blockIdx.y * MB;
  const int NCHT = gridDim.x * NB;         // total channels in wt2

  // per-lane LDS byte offsets for the 9 shifts (row = wm*32 + l31)
  int rb[9];
  {
    const int r = wm * 32 + l31;
    const int bl = r >> (2 * LOGS);
    const int rr = r & (SS - 1);
    const int sy = rr >> LOGS, sx = rr & (SIN - 1);
    #pragma unroll
    for (int dyi = 0; dyi < 3; ++dyi)
      #pragma unroll
      for (int dxi = 0; dxi < 3; ++dxi) {
        const int ny = sy + dyi - 1, nx = sx + dxi - 1;
        const bool ok = (ny >= 0 && ny < SIN && nx >= 0 && nx < SIN);
        const int rp = ok ? ((bl << (2 * LOGS)) + (ny << LOGS) + nx) : MB;
        rb[dyi * 3 + dxi] = (rp << 7) | ((rp & 7) << 4);
      }
  }
  if (t < 16) {  // zero sentinel row of both buffers
    s16x8 z = {};
    const int buf = t >> 3;
    *reinterpret_cast<s16x8*>(As + buf * BUFW + MB * 64 + (t & 7) * 8) = z;
  }

  f32x16 acc[2][2];
  #pragma unroll
  for (int py = 0; py < 2; ++py)
    #pragma unroll
    for (int px = 0; px < 2; ++px) acc[py][px] = (f32x16)(0.f);

  const int chb = bx * NB + wn * 32;              // wave channel base (wt2-local)
  const int ocw = chb + l31;                      // wt2-local out channel
  // per-lane coalesced B base: 64 lanes span 1KB contiguous
  const u16* wlane = wt + (size_t)(chb + l31) * 16 + kl2 * 8;
  const size_t nstride = (size_t)NCHT * 16;       // elems per (tap,kb) slice

  // staging geometry: row = p*64 + (t>>3), 16B at col (t&7)*8
  const int srow = t >> 3;
  const int scol = (t & 7) * 8;
  const u16* gsrc = in + (size_t)(R0 + srow) * CIN + scol;

  s16x8 sreg[NPASS];
  #pragma unroll
  for (int p = 0; p < NPASS; ++p)
    sreg[p] = *reinterpret_cast<const s16x8*>(gsrc + (size_t)p * 64 * CIN);

  int cur = 0;
  for (int s = 0; s < NSTEP; ++s) {
    u16* dbuf = As + cur * BUFW;
    #pragma unroll
    for (int p = 0; p < NPASS; ++p) {
      const int row = p * 64 + srow;
      const int db = row * 128 + ((scol * 2) ^ ((row & 7) << 4));
      *reinterpret_cast<s16x8*>((char*)dbuf + db) = sreg[p];
    }
    if (s + 1 < NSTEP) {
      const u16* gn = gsrc + (s + 1) * 64;
      #pragma unroll
      for (int p = 0; p < NPASS; ++p)
        sreg[p] = *reinterpret_cast<const s16x8*>(gn + (size_t)p * 64 * CIN);
    }
    lds_barrier();   // lgkmcnt(0) only; prefetch stays in flight

    const u16* Ab = As + cur * BUFW;
    #pragma unroll
    for (int ksub = 0; ksub < 4; ++ksub) {
      const int kb = s * 4 + ksub;
      // B fragments, coalesced (identical across wm-waves -> L1 dedup)
      s16x8 bf[2][2][2][2];
      #pragma unroll
      for (int py = 0; py < 2; ++py)
        #pragma unroll
        for (int px = 0; px < 2; ++px)
          #pragma unroll
          for (int jy = 0; jy < 2; ++jy)
            #pragma unroll
            for (int jx = 0; jx < 2; ++jx) {
              const int tap = KYT[py][jy] * 4 + KYT[px][jx];
              bf[py][px][jy][jx] = *reinterpret_cast<const s16x8*>(
                  wlane + (size_t)(tap * KB + kb) * nstride);
            }
      // A fragments: 9 shifts
      const int koff = ksub * 32 + kl2 * 16;
      s16x8 af[9];
      #pragma unroll
      for (int s9 = 0; s9 < 9; ++s9)
        af[s9] = *reinterpret_cast<const s16x8*>((const char*)Ab + (rb[s9] ^ koff));
      __builtin_amdgcn_s_setprio(1);
      #pragma unroll
      for (int py = 0; py < 2; ++py)
        #pragma unroll
        for (int px = 0; px < 2; ++px)
          #pragma unroll
          for (int jy = 0; jy < 2; ++jy)
            #pragma unroll
            for (int jx = 0; jx < 2; ++jx) {
              const int s9 = (DYT[py][jy] + 1) * 3 + (DYT[px][jx] + 1);
              acc[py][px] = __builtin_amdgcn_mfma_f32_32x32x16_bf16(
                  af[s9], bf[py][px][jy][jx], acc[py][px], 0, 0, 0);
            }
      __builtin_amdgcn_s_setprio(0);
    }
    cur ^= 1;
  }

  // epilogue: store + fused per-channel BN partials (fp32, pre-rounding)
  const float bo = bias[o_gbase + ocw];
  const int B0 = blockIdx.y * MBATCH;
  float s_ = 0.f, q_ = 0.f;
  #pragma unroll
  for (int i = 0; i < 16; ++i) {
    const int rl_ = (i & 3) + 8 * (i >> 2) + 4 * kl2;
    const int r = wm * 32 + rl_;
    const int bl = r >> (2 * LOGS);
    const int rr = r & (SS - 1);
    const int sy = rr >> LOGS, sx = rr & (SIN - 1);
    const size_t ob = (size_t)(B0 + bl) * 4 * SS;
    #pragma unroll
    for (int py = 0; py < 2; ++py)
      #pragma unroll
      for (int px = 0; px < 2; ++px) {
        const int od = (2 * sy + py) * (2 * SIN) + 2 * sx + px;
        const float v = acc[py][px][i] + bo;
        s_ += v;
        q_ = fmaf(v, v, q_);
        outp[(ob + od) * COUT_STORE + ocw] = f2bf(v);
      }
  }
  s_ += __shfl_xor(s_, 32);
  q_ += __shfl_xor(q_, 32);
  if (lane < 32) {
    sred[wave * 32 + l31] = s_;
    sred[256 + wave * 32 + l31] = q_;
  }
  __syncthreads();
  if (t < WN * 32) {
    const int wnr = t >> 5;
    const int ch = t & 31;
    float ss = 0.f, qq = 0.f;
    #pragma unroll
    for (int w = 0; w < WM; ++w) {
      ss += sred[(w * WN + wnr) * 32 + ch];
      qq += sred[256 + (w * WN + wnr) * 32 + ch];
    }
    const int c = bx * NB + wnr * 32 + ch;
    spp[(size_t)blockIdx.y * COUT_STORE + c] = ss;
    sqpp[(size_t)blockIdx.y * COUT_STORE + c] = qq;
  }
}

// ---------------- conv4: fused BN-affine+tanh + convT(128->1) + sigmoid -----
__global__ __launch_bounds__(256) void conv4_kernel(const u16* __restrict__ h3c,
                                                    const float* __restrict__ ac,
                                                    const float* __restrict__ bc,
                                                    const float* __restrict__ w4,
                                                    const float* __restrict__ b4,
                                                    float* __restrict__ outp,
                                                    int cbase, int last) {
  const int b = blockIdx.x;
  const int t = threadIdx.x;
  __shared__ float wsh[32 * 16];
  __shared__ float is[32 * 257];
  for (int i = t; i < 512; i += 256) wsh[i] = w4[cbase * 16 + i];
  const int cq = (t & 3) * 8;
  float av[8], bv[8];
  *reinterpret_cast<float4*>(av)     = *reinterpret_cast<const float4*>(ac + cq);
  *reinterpret_cast<float4*>(av + 4) = *reinterpret_cast<const float4*>(ac + cq + 4);
  *reinterpret_cast<float4*>(bv)     = *reinterpret_cast<const float4*>(bc + cq);
  *reinterpret_cast<float4*>(bv + 4) = *reinterpret_cast<const float4*>(bc + cq + 4);
  #pragma unroll
  for (int p = 0; p < 4; ++p) {
    const int idx8 = p * 256 + t;
    const int s = idx8 >> 2;
    union { s16x8 v8; u16 h[8]; } r;
    r.v8 = *reinterpret_cast<const s16x8*>(h3c + ((size_t)b * 256 + s) * 32 + cq);
    #pragma unroll
    for (int q = 0; q < 8; ++q)
      is[(cq + q) * 257 + s] = tanhf(fmaf(bf2f(r.h[q]), av[q], bv[q]));
  }
  __syncthreads();
  float acc[4] = {0.f, 0.f, 0.f, 0.f};
  const int ox = t & 31;
  const int oy0 = t >> 5;
  for (int c = 0; c < 32; ++c) {
    #pragma unroll
    for (int k = 0; k < 4; ++k) {
      const int oy = oy0 + 8 * k;
      #pragma unroll
      for (int jy = 0; jy < 2; ++jy) {
        const int ky = 2 * jy + 1 - (oy & 1);
        const int iyn = oy + 1 - ky;
        if ((unsigned)iyn < 32u) {
          const int iy = iyn >> 1;
          #pragma unroll
          for (int jx = 0; jx < 2; ++jx) {
            const int kx = 2 * jx + 1 - (ox & 1);
            const int ixn = ox + 1 - kx;
            if ((unsigned)ixn < 32u) {
              const int ix = ixn >> 1;
              acc[k] = fmaf(is[c * 257 + iy * 16 + ix], wsh[c * 16 + ky * 4 + kx], acc[k]);
            }
          }
        }
      }
    }
  }
  #pragma unroll
  for (int k = 0; k < 4; ++k) {
    const int oy = oy0 + 8 * k;
    const size_t ob = (size_t)b * 1024 + oy * 32 + ox;
    const float base = (cbase == 0) ? b4[0] : outp[ob];
    const float v = base + acc[k];
    outp[ob] = last ? (1.0f / (1.0f + expf(-v))) : v;
  }
}

// ----------------------------------------------------------------------------
extern "C" void kernel_launch(void* const* d_in, const int* in_sizes, int n_in,
                              void* d_out, int out_size, void* d_ws, size_t ws_size,
                              hipStream_t stream) {
  (void)in_sizes; (void)n_in; (void)out_size; (void)ws_size;
  const float* x   = (const float*)d_in[0];
  const float* w1  = (const float*)d_in[1];
  const float* b1  = (const float*)d_in[2];
  const float* g1  = (const float*)d_in[3];
  const float* be1 = (const float*)d_in[4];
  const float* w2  = (const float*)d_in[5];
  const float* b2  = (const float*)d_in[6];
  const float* g2  = (const float*)d_in[7];
  const float* be2 = (const float*)d_in[8];
  const float* w3  = (const float*)d_in[9];
  const float* b3  = (const float*)d_in[10];
  const float* g3  = (const float*)d_in[11];
  const float* be3 = (const float*)d_in[12];
  const float* w4  = (const float*)d_in[13];
  const float* b4  = (const float*)d_in[14];

  char* ws = (char*)d_ws;
  u16*   y2   = (u16*)(ws + 0);
  u16*   y1   = (u16*)(ws + 67108864);
  u16*   y3c  = (u16*)(ws + 100663296);
  u16*   w1t  = (u16*)(ws + 100663296);   // dead after conv1 (aliases y3c)
  u16*   w2t  = (u16*)(ws + 117047296);   // dead after conv2 (aliases y3c)
  float* vals = (float*)(ws + 134217728);
  int*   idxs = (int*)(ws + 134627328);
  float* sp   = (float*)(ws + 134217728); // post-conv1 (aliases vals)
  float* sqp  = (float*)(ws + 134479872);
  float* ac   = (float*)(ws + 134742016);
  float* bc   = (float*)(ws + 134744064);
  u16*   w3tc = (u16*)(ws + 134746112);   // 256KB per-chunk w3 transpose
  float* outp = (float*)d_out;

  // precomputes + truncation vector
  w1t_kernel<<<1000, 256, 0, stream>>>(w1, w1t);
  wt2_kernel<512, 256><<<dim3(32, 8), 256, 0, stream>>>(w2, w2t, 0, 256);
  topk_kernel<<<512, 256, 0, stream>>>(x, vals, idxs);

  // layer 1
  conv1_kernel<<<2048, 256, 0, stream>>>(vals, idxs, w1t, b1, y1);
  bnstats_kernel<<<dim3(4, 128), 256, 0, stream>>>(y1, sp, sqp, 512, 128, 32768);
  bnfin_kernel<<<2, 256, 0, stream>>>(sp, sqp, g1, be1, ac, bc, 9, 128, 1.0f / 32768.0f);
  bnact_kernel<<<8192, 256, 0, stream>>>(y1, ac, bc, 511);

  // layer 2: convT 512->256 on 32x32 MFMA, coalesced B, fused stats
  convt_mfma<4, 512, 4, 2, 8, 256><<<dim3(4, 256), 512, 0, stream>>>(
      y1, w2t, b2, y2, sp, sqp, 0);
  bnfin_kernel<<<1, 256, 0, stream>>>(sp, sqp, g2, be2, ac, bc, 8, 256, 1.0f / 131072.0f);
  bnact_kernel<<<16384, 256, 0, stream>>>(y2, ac, bc, 255);

  // layer 3+4: convT 256->128 in 4 chunks of 32 oc (per-chunk wt2 transpose);
  // fused stats; conv4 applies BN-affine+tanh and accumulates into d_out
  for (int ch = 0; ch < 4; ++ch) {
    const int cb = ch * 32;
    wt2_kernel<256, 128><<<dim3(16, 1), 256, 0, stream>>>(w3, w3tc, cb, 32);
    convt_mfma<8, 256, 8, 1, 4, 32><<<dim3(1, 512), 512, 0, stream>>>(
        y2, w3tc, b3, y3c, sp, sqp, cb);
    bnfin_kernel<<<1, 256, 0, stream>>>(sp, sqp, g3 + cb, be3 + cb, ac, bc, 5, 512,
                                        1.0f / 524288.0f);
    conv4_kernel<<<2048, 256, 0, stream>>>(y3c, ac, bc, w4, b4, outp, cb, ch == 3);
  }
}